// Round 6
// baseline (2475.115 us; speedup 1.0000x reference)
//
#include <hip/hip_runtime.h>
#include <hip/hip_bf16.h>
#include <math.h>

// Problem constants (fixed by the reference)
#define TT 256   // timesteps
#define BB 256   // batch
#define II 128   // input features (layer 0)
#define HH 512   // hidden
#define OO 128   // output features
#define WW 32    // output window

// Bounded-spin cap: on cap-trip the kernel free-runs (wrong answer, visible
// in absmax) instead of hanging the container.
#define SPIN_CAP 40000

typedef __bf16 bf16x8 __attribute__((ext_vector_type(8)));
typedef float  f32x4  __attribute__((ext_vector_type(4)));

// ---------------- fast gate functions (v_exp_f32 = 2^x, v_rcp_f32) ----------------
__device__ __forceinline__ float fast_sigm(float x) {
    float e = __builtin_amdgcn_exp2f(-1.442695040889f * x);
    return __builtin_amdgcn_rcpf(1.0f + e);
}
__device__ __forceinline__ float fast_tanh(float x) {
    float e = __builtin_amdgcn_exp2f(2.885390081777f * x);
    return 1.0f - 2.0f * __builtin_amdgcn_rcpf(1.0f + e);
}

// ---------------- cast fp32 -> bf16 (plain) ----------------
__global__ void cast_f32_bf16(const float* __restrict__ in,
                              __bf16* __restrict__ out, int n) {
    int i = blockIdx.x * 256 + threadIdx.x;
    if (i < n) out[i] = (__bf16)in[i];
}

// ---------------- weight prepack ----------------
// dst row' = jb*64 + g*16 + jj  <->  orig gate-row = g*512 + jb*16 + jj
// dst row k-layout = [ w_ih (KIN) ; w_hh (512) ]   (bf16, plain)
__global__ void pack_w_kernel(const float* __restrict__ wih,
                              const float* __restrict__ whh,
                              __bf16* __restrict__ dst, int KIN) {
    int idx = blockIdx.x * 256 + threadIdx.x;
    int KE8 = (KIN + 512) >> 3;
    int total = 2048 * KE8;
    if (idx >= total) return;
    int row = idx / KE8, k8 = idx - row * KE8;
    int jb = row >> 6, g = (row >> 4) & 3, jj = row & 15;
    int orig = g * 512 + jb * 16 + jj;
    int k = k8 * 8;
    const float* src = (k < KIN) ? (wih + (size_t)orig * KIN + k)
                                 : (whh + (size_t)orig * 512 + (k - KIN));
    __bf16* d = dst + (size_t)row * (KIN + 512) + k;
    #pragma unroll
    for (int i = 0; i < 8; ++i) d[i] = (__bf16)src[i];
}

// ---------------- global -> LDS staging (linear, chunk-padded 1024->1040) ----------------
// 4 waves split nchunk 1024B chunks; chunk c lands at c*1040 in LDS.
__device__ __forceinline__ void stage_tile(char* lds, const char* g, int nchunk,
                                           int wv, int l) {
    const int per = nchunk >> 2;
    const char* gp = g + (size_t)l * 16;
    for (int i = 0; i < per; ++i) {
        int c = wv * per + i;
        __builtin_amdgcn_global_load_lds(
            (const __attribute__((address_space(1))) void*)(gp + c * 1024),
            (__attribute__((address_space(3))) void*)(lds + c * 1040),
            16, 0, 0);
    }
}

// ---------------- MFMA over a staged tile: acc += tile * w[S..S+N) ----------------
template <int N, int S, int M>
__device__ __forceinline__ void mm_tile(const char* base, int off0, int off1,
                                        const bf16x8 (&w)[M], f32x4& a0, f32x4& a1) {
    #pragma unroll
    for (int kk = 0; kk < N; ++kk) {
        bf16x8 x0 = *(const bf16x8*)(base + off0 + kk * 64);
        bf16x8 x1 = *(const bf16x8*)(base + off1 + kk * 64);
        a0 = __builtin_amdgcn_mfma_f32_16x16x32_bf16(x0, w[S + kk], a0, 0, 0, 0);
        a1 = __builtin_amdgcn_mfma_f32_16x16x32_bf16(x1, w[S + kk], a1, 0, 0, 0);
    }
}

__device__ __forceinline__ void put_g(float (*sg)[32][18], int wv, int l,
                                      const f32x4& a0, const f32x4& a1) {
    #pragma unroll
    for (int r = 0; r < 4; ++r) {
        sg[wv][(l >> 4) * 4 + r][l & 15] = a0[r];
        sg[wv][16 + (l >> 4) * 4 + r][l & 15] = a1[r];
    }
}

// ---------------- elementwise cell update (2 elems/thread) ----------------
__device__ __forceinline__ void cell_update(const float (*sg)[32][18],
                                            const float (&br)[4][2], float (&cc)[2],
                                            bool first, char* dst, int eb, int ej) {
    union { __bf16 hv[2]; unsigned u; } pk;
    #pragma unroll
    for (int q = 0; q < 2; ++q) {
        float xi = sg[0][eb][ej + q] + br[0][q];
        float xf = sg[1][eb][ej + q] + br[1][q];
        float xg = sg[2][eb][ej + q] + br[2][q];
        float xo = sg[3][eb][ej + q] + br[3][q];
        float iv = fast_sigm(xi), fv = fast_sigm(xf);
        float gv = fast_tanh(xg), ov = fast_sigm(xo);
        cc[q] = first ? iv * gv : fmaf(fv, cc[q], iv * gv);
        pk.hv[q] = (__bf16)(ov * fast_tanh(cc[q]));
    }
    *(unsigned*)dst = pk.u;
}

// ---------------- persistent pipelined 3-layer LSTM ----------------
// Global step s: layer0 computes t=s, layer1 t=s-1, layer2 t=s-2.
// ONE group barrier per s (258 total instead of 768).
// LDS ~133KB -> exactly 1 block/CU (XCD regrouping relies on this).
__global__ __launch_bounds__(256, 1) void lstm_persist(
    const __bf16* __restrict__ xb,
    const __bf16* __restrict__ pw0, const __bf16* __restrict__ pw1,
    const __bf16* __restrict__ pw2,
    const float* __restrict__ b0, const float* __restrict__ b1,
    const float* __restrict__ b2,
    __bf16* __restrict__ h0, __bf16* __restrict__ h1, __bf16* __restrict__ h2,
    int* ctrA, int* hs)
{
    __shared__ __align__(16) char s_x[8320];      // 8 chunks @1040
    __shared__ __align__(16) char s_h0[33280];    // 32 chunks @1040
    __shared__ __align__(16) char s_h1[33280];
    __shared__ __align__(16) char s_h2[33280];
    __shared__ float s_g0[4][32][18], s_g1[4][32][18], s_g2[4][32][18];
    __shared__ int s_grp, s_jb, s_same;

    const int tid = threadIdx.x;
    const int wv = tid >> 6, l = tid & 63;

    // ---- dynamic XCD regrouping: group = PHYSICAL XCD, jb = arrival slot ----
    if (tid == 0) {
        unsigned xcc = 0;
        asm volatile("s_getreg_b32 %0, hwreg(HW_REG_XCC_ID)" : "=s"(xcc));
        xcc &= 7;
        int slot = __hip_atomic_fetch_add(hs + xcc, 1, __ATOMIC_RELAXED,
                                          __HIP_MEMORY_SCOPE_AGENT);
        __hip_atomic_fetch_add(hs + 8, 1, __ATOMIC_RELEASE, __HIP_MEMORY_SCOPE_AGENT);
        int spins = 0;
        while (__hip_atomic_load(hs + 8, __ATOMIC_ACQUIRE, __HIP_MEMORY_SCOPE_AGENT) < 256) {
            __builtin_amdgcn_s_sleep(1);
            if (++spins > SPIN_CAP) break;
        }
        int ok = 1;
        #pragma unroll
        for (int x = 0; x < 8; ++x)
            ok &= (__hip_atomic_load(hs + x, __ATOMIC_RELAXED,
                                     __HIP_MEMORY_SCOPE_AGENT) == 32);
        s_same = ok;
        s_grp = ok ? (int)xcc : (int)(blockIdx.x & 7);
        s_jb  = ok ? slot     : (int)(blockIdx.x >> 3);
    }
    __syncthreads();
    const bool same = (s_same != 0);
    const int  grp  = s_grp, jb = s_jb;
    int* ctr = ctrA + grp * 64;

    // ---- weights -> VGPRs: per wave 16 gate-rows per layer, B-frag layout ----
    bf16x8 w0[20], w1[32], w2[32];
    {
        const __bf16* rp = pw0 + (size_t)(jb * 64 + wv * 16 + (l & 15)) * 640 + (l >> 4) * 8;
        #pragma unroll
        for (int kk = 0; kk < 20; ++kk) w0[kk] = *(const bf16x8*)(rp + kk * 32);
    }
    {
        const __bf16* rp = pw1 + (size_t)(jb * 64 + wv * 16 + (l & 15)) * 1024 + (l >> 4) * 8;
        #pragma unroll
        for (int kk = 0; kk < 32; ++kk) w1[kk] = *(const bf16x8*)(rp + kk * 32);
    }
    {
        const __bf16* rp = pw2 + (size_t)(jb * 64 + wv * 16 + (l & 15)) * 1024 + (l >> 4) * 8;
        #pragma unroll
        for (int kk = 0; kk < 32; ++kk) w2[kk] = *(const bf16x8*)(rp + kk * 32);
    }

    // ---- bias + cell state in registers ----
    const int eb = tid >> 3;          // batch-local 0..31
    const int ej = (tid & 7) * 2;     // hidden-local 0..14 step 2
    float br0[4][2], br1[4][2], br2[4][2], cc0[2], cc1[2], cc2[2];
    #pragma unroll
    for (int g = 0; g < 4; ++g) {
        br0[g][0] = b0[g * 512 + jb * 16 + ej]; br0[g][1] = b0[g * 512 + jb * 16 + ej + 1];
        br1[g][0] = b1[g * 512 + jb * 16 + ej]; br1[g][1] = b1[g * 512 + jb * 16 + ej + 1];
        br2[g][0] = b2[g * 512 + jb * 16 + ej]; br2[g][1] = b2[g * 512 + jb * 16 + ej + 1];
    }
    cc0[0] = cc0[1] = cc1[0] = cc1[1] = cc2[0] = cc2[1] = 0.0f;

    // ---- per-lane LDS fragment offsets (chunk-padded, stride 1040) ----
    const int Cq = (l >> 4) * 16;
    const int row0 = (l & 15), row1 = 16 + (l & 15);
    const int xoff0 = (row0 >> 2) * 1040 + (row0 & 3) * 256 + Cq;   // x: 256B rows, 4/chunk
    const int xoff1 = (row1 >> 2) * 1040 + (row1 & 3) * 256 + Cq;
    const int hoff0 = row0 * 1040 + Cq;                             // h: 1024B rows
    const int hoff1 = row1 * 1040 + Cq;

    const int ebase = jb * 16 + ej;    // hidden index of this thread's 2 elems

    // prologue: stage x(0)
    stage_tile(s_x, (const char*)xb + (size_t)(grp * 32) * 256, 8, wv, l);

    for (int s = 0; s < TT + 2; ++s) {
        // ---- stage inputs written last step (group-local, L2-hot) ----
        if (s >= 1 && s <= 256)
            stage_tile(s_h0, (const char*)h0 + (size_t)((s - 1) * 256 + grp * 32) * 1024,
                       32, wv, l);
        if (s >= 2)
            stage_tile(s_h1, (const char*)h1 + (size_t)((s - 2) * 256 + grp * 32) * 1024,
                       32, wv, l);
        if (s >= 3)
            stage_tile(s_h2, (const char*)h2 + (size_t)((s - 3) * 256 + grp * 32) * 1024,
                       32, wv, l);
        __syncthreads();   // all stages (incl. x from prev spin) complete

        // ---- MFMA phase: 3 skewed layers ----
        if (s < 256) {                       // layer 0 @ t=s
            f32x4 a0 = {}, a1 = {};
            mm_tile<4, 0>(s_x, xoff0, xoff1, w0, a0, a1);
            if (s >= 1) mm_tile<16, 4>(s_h0, hoff0, hoff1, w0, a0, a1);
            put_g(s_g0, wv, l, a0, a1);
        }
        if (s >= 1 && s <= 256) {            // layer 1 @ t=s-1
            f32x4 a0 = {}, a1 = {};
            mm_tile<16, 0>(s_h0, hoff0, hoff1, w1, a0, a1);
            if (s >= 2) mm_tile<16, 16>(s_h1, hoff0, hoff1, w1, a0, a1);
            put_g(s_g1, wv, l, a0, a1);
        }
        if (s >= 2) {                        // layer 2 @ t=s-2
            f32x4 a0 = {}, a1 = {};
            mm_tile<16, 0>(s_h1, hoff0, hoff1, w2, a0, a1);
            if (s >= 3) mm_tile<16, 16>(s_h2, hoff0, hoff1, w2, a0, a1);
            put_g(s_g2, wv, l, a0, a1);
        }
        __syncthreads();

        // ---- elementwise cell updates ----
        if (s < 256)
            cell_update(s_g0, br0, cc0, s == 0,
                        (char*)h0 + (size_t)((s * 256 + grp * 32 + eb) * 512 + ebase) * 2,
                        eb, ej);
        if (s >= 1 && s <= 256)
            cell_update(s_g1, br1, cc1, s == 1,
                        (char*)h1 + (size_t)(((s - 1) * 256 + grp * 32 + eb) * 512 + ebase) * 2,
                        eb, ej);
        if (s >= 2)
            cell_update(s_g2, br2, cc2, s == 2,
                        (char*)h2 + (size_t)(((s - 2) * 256 + grp * 32 + eb) * 512 + ebase) * 2,
                        eb, ej);

        // ---- group barrier (32 same-XCD blocks); x(s+1) prefetch overlaps spin ----
        if (!same) __threadfence();      // cross-XCD release (fallback only)
        __syncthreads();                 // vmcnt(0) drain: h-stores visible in L2
        if (tid == 0)
            __hip_atomic_fetch_add(ctr, 1, __ATOMIC_RELAXED, __HIP_MEMORY_SCOPE_AGENT);
        if (s + 1 < 256)
            stage_tile(s_x, (const char*)xb + (size_t)((s + 1) * 256 + grp * 32) * 256,
                       8, wv, l);
        if (tid == 0) {
            int tgt = 32 * (s + 1);
            int spins = 0;
            while (__hip_atomic_load(ctr, __ATOMIC_RELAXED, __HIP_MEMORY_SCOPE_AGENT) < tgt) {
                __builtin_amdgcn_s_sleep(1);
                if (++spins > SPIN_CAP) break;   // bounded: fail visibly, never hang
            }
        }
        __syncthreads();
        if (!same) __threadfence();      // cross-XCD acquire (fallback only)
    }
}

// ---------------- final projection (h2 is plain [T*B, HH]) ----------------
__global__ __launch_bounds__(256) void proj_kernel(
    const __bf16* __restrict__ A,    // [8192, HH]
    const __bf16* __restrict__ Wo,   // [OO, HH]
    const float*  __restrict__ bo,   // [OO]
    float*        __restrict__ out)  // [8192, OO]
{
    const int r0   = blockIdx.x * 32;
    const int wave = threadIdx.x >> 6;
    const int lane = threadIdx.x & 63;
    const int n0   = wave * 32;
    const int arow = lane & 15;
    const int koff = (lane >> 4) * 8;

    f32x4 acc[2][2] = {};
    const __bf16* a0p = A  + (size_t)(r0 + arow) * HH + koff;
    const __bf16* a1p = A  + (size_t)(r0 + 16 + arow) * HH + koff;
    const __bf16* w0p = Wo + (size_t)(n0 + arow) * HH + koff;
    const __bf16* w1p = Wo + (size_t)(n0 + 16 + arow) * HH + koff;
    for (int k0 = 0; k0 < HH; k0 += 32) {
        bf16x8 a0 = *(const bf16x8*)(a0p + k0);
        bf16x8 a1 = *(const bf16x8*)(a1p + k0);
        bf16x8 w0 = *(const bf16x8*)(w0p + k0);
        bf16x8 w1 = *(const bf16x8*)(w1p + k0);
        acc[0][0] = __builtin_amdgcn_mfma_f32_16x16x32_bf16(a0, w0, acc[0][0], 0, 0, 0);
        acc[0][1] = __builtin_amdgcn_mfma_f32_16x16x32_bf16(a0, w1, acc[0][1], 0, 0, 0);
        acc[1][0] = __builtin_amdgcn_mfma_f32_16x16x32_bf16(a1, w0, acc[1][0], 0, 0, 0);
        acc[1][1] = __builtin_amdgcn_mfma_f32_16x16x32_bf16(a1, w1, acc[1][1], 0, 0, 0);
    }
    #pragma unroll
    for (int mi = 0; mi < 2; ++mi)
        #pragma unroll
        for (int ni = 0; ni < 2; ++ni)
            #pragma unroll
            for (int r = 0; r < 4; ++r) {
                int row = r0 + mi * 16 + ((lane >> 4) * 4) + r;
                int col = n0 + ni * 16 + (lane & 15);
                out[(size_t)row * OO + col] = acc[mi][ni][r] + bo[col];
            }
}

// ---------------- launch ----------------
extern "C" void kernel_launch(void* const* d_in, const int* in_sizes, int n_in,
                              void* d_out, int out_size, void* d_ws, size_t ws_size,
                              hipStream_t stream) {
    const float* x      = (const float*)d_in[0];
    const float* w_ih_0 = (const float*)d_in[1];
    const float* w_hh_0 = (const float*)d_in[2];
    const float* b_0    = (const float*)d_in[3];
    const float* w_ih_1 = (const float*)d_in[4];
    const float* w_hh_1 = (const float*)d_in[5];
    const float* b_1    = (const float*)d_in[6];
    const float* w_ih_2 = (const float*)d_in[7];
    const float* w_hh_2 = (const float*)d_in[8];
    const float* b_2    = (const float*)d_in[9];
    const float* w_out  = (const float*)d_in[10];
    const float* b_out  = (const float*)d_in[11];
    float* out = (float*)d_out;

    // ---- workspace carve-up ----
    char* ws = (char*)d_ws;
    size_t off = 0;
    __bf16* xb    = (__bf16*)(ws + off); off += (size_t)TT * BB * II * 2;      // 16.8 MB
    __bf16* pw0   = (__bf16*)(ws + off); off += (size_t)2048 * 640 * 2;        // 2.6 MB
    __bf16* pw1   = (__bf16*)(ws + off); off += (size_t)2048 * 1024 * 2;       // 4.2 MB
    __bf16* pw2   = (__bf16*)(ws + off); off += (size_t)2048 * 1024 * 2;
    __bf16* woutb = (__bf16*)(ws + off); off += (size_t)OO * HH * 2;
    __bf16* h0    = (__bf16*)(ws + off); off += (size_t)TT * BB * HH * 2;      // 67 MB
    __bf16* h1    = (__bf16*)(ws + off); off += (size_t)TT * BB * HH * 2;
    __bf16* h2    = (__bf16*)(ws + off); off += (size_t)TT * BB * HH * 2;
    int*    ctrA  = (int*)(ws + off);    off += (size_t)8 * 64 * 4;
    int*    hs    = (int*)(ws + off);    off += (size_t)64 * 4;
    (void)ws_size; (void)in_sizes; (void)n_in; (void)out_size;

    // ---- prepack ----
    {
        int n = TT * BB * II;
        cast_f32_bf16<<<(n + 255) / 256, 256, 0, stream>>>(x, xb, n);
        n = OO * HH;
        cast_f32_bf16<<<(n + 255) / 256, 256, 0, stream>>>(w_out, woutb, n);
        int t0 = 2048 * (640 / 8);
        pack_w_kernel<<<(t0 + 255) / 256, 256, 0, stream>>>(w_ih_0, w_hh_0, pw0, II);
        int t1 = 2048 * (1024 / 8);
        pack_w_kernel<<<(t1 + 255) / 256, 256, 0, stream>>>(w_ih_1, w_hh_1, pw1, HH);
        pack_w_kernel<<<(t1 + 255) / 256, 256, 0, stream>>>(w_ih_2, w_hh_2, pw2, HH);
    }
    hipMemsetAsync(ctrA, 0, (size_t)(8 * 64 + 64) * 4, stream);

    // ---- persistent pipelined 3-layer LSTM: 256 blocks (1/CU) ----
    lstm_persist<<<256, 256, 0, stream>>>(xb, pw0, pw1, pw2, b_0, b_1, b_2,
                                          h0, h1, h2, ctrA, hs);

    // ---- projection over last WW timesteps ----
    const __bf16* A = h2 + (size_t)(TT - WW) * BB * HH;
    proj_kernel<<<(WW * BB) / 32, 256, 0, stream>>>(A, woutb, b_out, out);
}

// Round 8
// 1783.254 us; speedup vs baseline: 1.3880x; 1.3880x over previous
//
#include <hip/hip_runtime.h>
#include <hip/hip_bf16.h>
#include <math.h>

// Problem constants (fixed by the reference)
#define TT 256   // timesteps
#define BB 256   // batch
#define II 128   // input features (layer 0)
#define HH 512   // hidden
#define OO 128   // output features
#define WW 32    // output window

// Bounded-spin cap: on cap-trip the kernel free-runs (wrong answer, visible
// in absmax) instead of hanging the container.
#define SPIN_CAP 40000

typedef __bf16 bf16x8 __attribute__((ext_vector_type(8)));
typedef float  f32x4  __attribute__((ext_vector_type(4)));

#define MFMA(a, b, c) __builtin_amdgcn_mfma_f32_16x16x32_bf16((a), (b), (c), 0, 0, 0)

// ---------------- fast gate functions (v_exp_f32 = 2^x, v_rcp_f32) ----------------
__device__ __forceinline__ float fast_sigm(float x) {
    float e = __builtin_amdgcn_exp2f(-1.442695040889f * x);
    return __builtin_amdgcn_rcpf(1.0f + e);
}
__device__ __forceinline__ float fast_tanh(float x) {
    float e = __builtin_amdgcn_exp2f(2.885390081777f * x);
    return 1.0f - 2.0f * __builtin_amdgcn_rcpf(1.0f + e);
}

// ---------------- cast fp32 -> bf16 (plain) ----------------
__global__ void cast_f32_bf16(const float* __restrict__ in,
                              __bf16* __restrict__ out, int n) {
    int i = blockIdx.x * 256 + threadIdx.x;
    if (i < n) out[i] = (__bf16)in[i];
}

// ---------------- weight prepack ----------------
// dst row' = jb*64 + g*16 + jj  <->  orig gate-row = g*512 + jb*16 + jj
// dst row k-layout = [ w_ih (KIN) ; w_hh (512) ]   (bf16, plain)
__global__ void pack_w_kernel(const float* __restrict__ wih,
                              const float* __restrict__ whh,
                              __bf16* __restrict__ dst, int KIN) {
    int idx = blockIdx.x * 256 + threadIdx.x;
    int KE8 = (KIN + 512) >> 3;
    int total = 2048 * KE8;
    if (idx >= total) return;
    int row = idx / KE8, k8 = idx - row * KE8;
    int jb = row >> 6, g = (row >> 4) & 3, jj = row & 15;
    int orig = g * 512 + jb * 16 + jj;
    int k = k8 * 8;
    const float* src = (k < KIN) ? (wih + (size_t)orig * KIN + k)
                                 : (whh + (size_t)orig * 512 + (k - KIN));
    __bf16* d = dst + (size_t)row * (KIN + 512) + k;
    #pragma unroll
    for (int i = 0; i < 8; ++i) d[i] = (__bf16)src[i];
}

// ---------------- global -> LDS staging (linear, chunk-padded 1024->1040) ----------------
// 8 waves split nchunk 1024B chunks; chunk c lands at c*1040 in LDS.
__device__ __forceinline__ void stage8(char* lds, const char* g, int nchunk,
                                       int wv, int l) {
    const int per = nchunk >> 3;
    const char* gp = g + (size_t)l * 16;
    for (int i = 0; i < per; ++i) {
        int c = wv * per + i;
        __builtin_amdgcn_global_load_lds(
            (const __attribute__((address_space(1))) void*)(gp + c * 1024),
            (__attribute__((address_space(3))) void*)(lds + c * 1040),
            16, 0, 0);
    }
}

// ---------------- persistent pipelined 3-layer LSTM ----------------
// Global step s: layer0 t=s, layer1 t=s-1, layer2 t=s-2. One flag-barrier/step.
// 8 waves = (gate 0..3) x (K-half 0..1): per-wave weights 42 bf16x8 = 168 VGPR
// -> RESIDENT (round-6 failure: 336/wave forced reload from L3 every step).
// LDS 160,384 B -> exactly 1 block/CU (XCD regrouping relies on this).
__global__ __launch_bounds__(512, 2) void lstm_persist(
    const __bf16* __restrict__ xb,
    const __bf16* __restrict__ pw0, const __bf16* __restrict__ pw1,
    const __bf16* __restrict__ pw2,
    const float* __restrict__ b0, const float* __restrict__ b1,
    const float* __restrict__ b2,
    __bf16* __restrict__ h0, __bf16* __restrict__ h1, __bf16* __restrict__ h2,
    int* hs, int* flags)
{
    __shared__ __align__(16) char s_x[8320];      // 8 chunks @1040 (32 x-rows, 256B)
    __shared__ __align__(16) char s_h0[33280];    // 32 chunks @1040 (32 h-rows, 1024B)
    __shared__ __align__(16) char s_h1[33280];
    __shared__ __align__(16) char s_h2[33280];
    __shared__ float s_gA[4][2][32][17];          // [gate][khalf][batch][hidden]
    __shared__ float s_gB[4][2][32][17];
    __shared__ float s_gC[4][2][32][17];
    __shared__ int s_grp, s_jb, s_same;

    const int tid = threadIdx.x;
    const int wv = tid >> 6, l = tid & 63;
    const int g  = wv & 3;        // gate
    const int kh = wv >> 2;       // K-half

    // ---- dynamic XCD regrouping: group = PHYSICAL XCD, jb = arrival slot ----
    if (tid == 0) {
        unsigned xcc = 0;
        asm volatile("s_getreg_b32 %0, hwreg(HW_REG_XCC_ID)" : "=s"(xcc));
        xcc &= 7;
        int slot = __hip_atomic_fetch_add(hs + xcc, 1, __ATOMIC_RELAXED,
                                          __HIP_MEMORY_SCOPE_AGENT);
        __hip_atomic_fetch_add(hs + 8, 1, __ATOMIC_RELEASE, __HIP_MEMORY_SCOPE_AGENT);
        int spins = 0;
        while (__hip_atomic_load(hs + 8, __ATOMIC_ACQUIRE, __HIP_MEMORY_SCOPE_AGENT) < 256) {
            __builtin_amdgcn_s_sleep(1);
            if (++spins > SPIN_CAP) break;
        }
        int ok = 1;
        #pragma unroll
        for (int x = 0; x < 8; ++x)
            ok &= (__hip_atomic_load(hs + x, __ATOMIC_RELAXED,
                                     __HIP_MEMORY_SCOPE_AGENT) == 32);
        s_same = ok;
        s_grp = ok ? (int)xcc : (int)(blockIdx.x & 7);
        s_jb  = ok ? slot     : (int)(blockIdx.x >> 3);
    }
    __syncthreads();
    const bool same = (s_same != 0);
    const int  grp  = s_grp, jb = s_jb;
    int* myflag = flags + (size_t)(grp * 32 + jb) * 32;   // 128B-spread, single writer
    int* gflags = flags + (size_t)grp * 32 * 32;

    // ---- weights -> VGPRs (resident): per wave 16 gate-rows x K-half ----
    bf16x8 w0[10], w1[16], w2[16];
    {
        const __bf16* rp = pw0 + (size_t)(jb * 64 + g * 16 + (l & 15)) * 640 + (l >> 4) * 8;
        #pragma unroll
        for (int kk = 0; kk < 2; ++kk) w0[kk] = *(const bf16x8*)(rp + kh * 64 + kk * 32);
        #pragma unroll
        for (int kk = 0; kk < 8; ++kk) w0[2 + kk] = *(const bf16x8*)(rp + 128 + kh * 256 + kk * 32);
    }
    {
        const __bf16* rp = pw1 + (size_t)(jb * 64 + g * 16 + (l & 15)) * 1024 + (l >> 4) * 8;
        #pragma unroll
        for (int kk = 0; kk < 8; ++kk) {
            w1[kk]     = *(const bf16x8*)(rp + kh * 256 + kk * 32);
            w1[8 + kk] = *(const bf16x8*)(rp + 512 + kh * 256 + kk * 32);
        }
    }
    {
        const __bf16* rp = pw2 + (size_t)(jb * 64 + g * 16 + (l & 15)) * 1024 + (l >> 4) * 8;
        #pragma unroll
        for (int kk = 0; kk < 8; ++kk) {
            w2[kk]     = *(const bf16x8*)(rp + kh * 256 + kk * 32);
            w2[8 + kk] = *(const bf16x8*)(rp + 512 + kh * 256 + kk * 32);
        }
    }

    // ---- bias + cell state: 1 output element per thread ----
    const int eb = tid >> 4;      // batch-local 0..31
    const int ej = tid & 15;      // hidden-local 0..15
    float br0[4], br1[4], br2[4];
    #pragma unroll
    for (int g4 = 0; g4 < 4; ++g4) {
        br0[g4] = b0[g4 * 512 + jb * 16 + ej];
        br1[g4] = b1[g4 * 512 + jb * 16 + ej];
        br2[g4] = b2[g4 * 512 + jb * 16 + ej];
    }
    float c0 = 0.0f, c1 = 0.0f, c2 = 0.0f;

    // ---- per-lane LDS fragment offsets (chunk-padded, stride 1040) ----
    const int Cq = (l >> 4) * 16;
    const int r0 = l & 15, r1 = 16 + (l & 15);
    const int xo0 = (r0 >> 2) * 1040 + (r0 & 3) * 256 + Cq;   // x: 256B rows, 4/chunk
    const int xo1 = (r1 >> 2) * 1040 + (r1 & 3) * 256 + Cq;
    const int ho0 = r0 * 1040 + Cq;                            // h: 1024B rows
    const int ho1 = r1 * 1040 + Cq;
    const int khx = kh * 128;     // byte offset of this wave's x K-half
    const int khh = kh * 512;     // byte offset of this wave's h K-half

    // prologue: stage x(0)
    stage8(s_x, (const char*)xb + (size_t)(grp * 32) * 256, 8, wv, l);

    for (int s = 0; s < TT + 2; ++s) {
        // ---- stage inputs written last step (group-local, L2-hot) ----
        if (s >= 1 && s <= 256)
            stage8(s_h0, (const char*)h0 + (size_t)((s - 1) * 256 + grp * 32) * 1024, 32, wv, l);
        if (s >= 2)
            stage8(s_h1, (const char*)h1 + (size_t)((s - 2) * 256 + grp * 32) * 1024, 32, wv, l);
        if (s >= 3)
            stage8(s_h2, (const char*)h2 + (size_t)((s - 3) * 256 + grp * 32) * 1024, 32, wv, l);
        __syncthreads();   // all stages (incl. x from prev spin) complete

        // ---- MFMA phase: 3 skewed layers, this wave's (gate, K-half) ----
        if (s < TT) {                        // layer 0 @ t=s
            f32x4 a0 = {}, a1 = {};
            #pragma unroll
            for (int kk = 0; kk < 2; ++kk) {
                bf16x8 v0 = *(const bf16x8*)(s_x + xo0 + khx + kk * 64);
                bf16x8 v1 = *(const bf16x8*)(s_x + xo1 + khx + kk * 64);
                a0 = MFMA(v0, w0[kk], a0);
                a1 = MFMA(v1, w0[kk], a1);
            }
            if (s >= 1) {
                #pragma unroll
                for (int kk = 0; kk < 8; ++kk) {
                    bf16x8 v0 = *(const bf16x8*)(s_h0 + ho0 + khh + kk * 64);
                    bf16x8 v1 = *(const bf16x8*)(s_h0 + ho1 + khh + kk * 64);
                    a0 = MFMA(v0, w0[2 + kk], a0);
                    a1 = MFMA(v1, w0[2 + kk], a1);
                }
            }
            #pragma unroll
            for (int r = 0; r < 4; ++r) {
                s_gA[g][kh][(l >> 4) * 4 + r][l & 15]      = a0[r];
                s_gA[g][kh][16 + (l >> 4) * 4 + r][l & 15] = a1[r];
            }
        }
        if (s >= 1 && s <= 256) {            // layer 1 @ t=s-1
            f32x4 a0 = {}, a1 = {};
            #pragma unroll
            for (int kk = 0; kk < 8; ++kk) {
                bf16x8 v0 = *(const bf16x8*)(s_h0 + ho0 + khh + kk * 64);
                bf16x8 v1 = *(const bf16x8*)(s_h0 + ho1 + khh + kk * 64);
                a0 = MFMA(v0, w1[kk], a0);
                a1 = MFMA(v1, w1[kk], a1);
            }
            if (s >= 2) {
                #pragma unroll
                for (int kk = 0; kk < 8; ++kk) {
                    bf16x8 v0 = *(const bf16x8*)(s_h1 + ho0 + khh + kk * 64);
                    bf16x8 v1 = *(const bf16x8*)(s_h1 + ho1 + khh + kk * 64);
                    a0 = MFMA(v0, w1[8 + kk], a0);
                    a1 = MFMA(v1, w1[8 + kk], a1);
                }
            }
            #pragma unroll
            for (int r = 0; r < 4; ++r) {
                s_gB[g][kh][(l >> 4) * 4 + r][l & 15]      = a0[r];
                s_gB[g][kh][16 + (l >> 4) * 4 + r][l & 15] = a1[r];
            }
        }
        if (s >= 2) {                        // layer 2 @ t=s-2
            f32x4 a0 = {}, a1 = {};
            #pragma unroll
            for (int kk = 0; kk < 8; ++kk) {
                bf16x8 v0 = *(const bf16x8*)(s_h1 + ho0 + khh + kk * 64);
                bf16x8 v1 = *(const bf16x8*)(s_h1 + ho1 + khh + kk * 64);
                a0 = MFMA(v0, w2[kk], a0);
                a1 = MFMA(v1, w2[kk], a1);
            }
            if (s >= 3) {
                #pragma unroll
                for (int kk = 0; kk < 8; ++kk) {
                    bf16x8 v0 = *(const bf16x8*)(s_h2 + ho0 + khh + kk * 64);
                    bf16x8 v1 = *(const bf16x8*)(s_h2 + ho1 + khh + kk * 64);
                    a0 = MFMA(v0, w2[8 + kk], a0);
                    a1 = MFMA(v1, w2[8 + kk], a1);
                }
            }
            #pragma unroll
            for (int r = 0; r < 4; ++r) {
                s_gC[g][kh][(l >> 4) * 4 + r][l & 15]      = a0[r];
                s_gC[g][kh][16 + (l >> 4) * 4 + r][l & 15] = a1[r];
            }
        }
        __syncthreads();

        // ---- elementwise cell updates (sum the two K-half partials) ----
        if (s < TT) {
            float xi = s_gA[0][0][eb][ej] + s_gA[0][1][eb][ej] + br0[0];
            float xf = s_gA[1][0][eb][ej] + s_gA[1][1][eb][ej] + br0[1];
            float xg = s_gA[2][0][eb][ej] + s_gA[2][1][eb][ej] + br0[2];
            float xo = s_gA[3][0][eb][ej] + s_gA[3][1][eb][ej] + br0[3];
            float iv = fast_sigm(xi), fv = fast_sigm(xf);
            float gv = fast_tanh(xg), ov = fast_sigm(xo);
            c0 = (s == 0) ? iv * gv : fmaf(fv, c0, iv * gv);
            *(__bf16*)((char*)h0 +
                (size_t)((s * 256 + grp * 32 + eb) * 512 + jb * 16 + ej) * 2) =
                (__bf16)(ov * fast_tanh(c0));
        }
        if (s >= 1 && s <= 256) {
            float xi = s_gB[0][0][eb][ej] + s_gB[0][1][eb][ej] + br1[0];
            float xf = s_gB[1][0][eb][ej] + s_gB[1][1][eb][ej] + br1[1];
            float xg = s_gB[2][0][eb][ej] + s_gB[2][1][eb][ej] + br1[2];
            float xo = s_gB[3][0][eb][ej] + s_gB[3][1][eb][ej] + br1[3];
            float iv = fast_sigm(xi), fv = fast_sigm(xf);
            float gv = fast_tanh(xg), ov = fast_sigm(xo);
            c1 = (s == 1) ? iv * gv : fmaf(fv, c1, iv * gv);
            *(__bf16*)((char*)h1 +
                (size_t)(((s - 1) * 256 + grp * 32 + eb) * 512 + jb * 16 + ej) * 2) =
                (__bf16)(ov * fast_tanh(c1));
        }
        if (s >= 2) {
            float xi = s_gC[0][0][eb][ej] + s_gC[0][1][eb][ej] + br2[0];
            float xf = s_gC[1][0][eb][ej] + s_gC[1][1][eb][ej] + br2[1];
            float xg = s_gC[2][0][eb][ej] + s_gC[2][1][eb][ej] + br2[2];
            float xo = s_gC[3][0][eb][ej] + s_gC[3][1][eb][ej] + br2[3];
            float iv = fast_sigm(xi), fv = fast_sigm(xf);
            float gv = fast_tanh(xg), ov = fast_sigm(xo);
            c2 = (s == 2) ? iv * gv : fmaf(fv, c2, iv * gv);
            *(__bf16*)((char*)h2 +
                (size_t)(((s - 2) * 256 + grp * 32 + eb) * 512 + jb * 16 + ej) * 2) =
                (__bf16)(ov * fast_tanh(c2));
        }

        // ---- flag barrier (32 same-XCD blocks, no atomic contention) ----
        if (!same) __threadfence();      // cross-XCD release (fallback only)
        __syncthreads();                 // vmcnt(0) drain: h-stores visible in L2
        if (tid == 0)
            __hip_atomic_store(myflag, s + 1, __ATOMIC_RELAXED, __HIP_MEMORY_SCOPE_AGENT);
        if (s + 1 < TT)                  // x(s+1) prefetch overlaps the poll
            stage8(s_x, (const char*)xb + (size_t)((s + 1) * 256 + grp * 32) * 256, 8, wv, l);
        if (tid < 32) {                  // 32 lanes poll 32 flags in parallel
            int spins = 0;
            while (__hip_atomic_load(gflags + tid * 32, __ATOMIC_RELAXED,
                                     __HIP_MEMORY_SCOPE_AGENT) < s + 1) {
                __builtin_amdgcn_s_sleep(1);
                if (++spins > SPIN_CAP) break;   // bounded: fail visibly, never hang
            }
        }
        __syncthreads();
        if (!same) __threadfence();      // cross-XCD acquire (fallback only)
    }
}

// ---------------- final projection (h2 is plain [T*B, HH]) ----------------
__global__ __launch_bounds__(256) void proj_kernel(
    const __bf16* __restrict__ A,    // [8192, HH]
    const __bf16* __restrict__ Wo,   // [OO, HH]
    const float*  __restrict__ bo,   // [OO]
    float*        __restrict__ out)  // [8192, OO]
{
    const int r0   = blockIdx.x * 32;
    const int wave = threadIdx.x >> 6;
    const int lane = threadIdx.x & 63;
    const int n0   = wave * 32;
    const int arow = lane & 15;
    const int koff = (lane >> 4) * 8;

    f32x4 acc[2][2] = {};
    const __bf16* a0p = A  + (size_t)(r0 + arow) * HH + koff;
    const __bf16* a1p = A  + (size_t)(r0 + 16 + arow) * HH + koff;
    const __bf16* w0p = Wo + (size_t)(n0 + arow) * HH + koff;
    const __bf16* w1p = Wo + (size_t)(n0 + 16 + arow) * HH + koff;
    for (int k0 = 0; k0 < HH; k0 += 32) {
        bf16x8 a0 = *(const bf16x8*)(a0p + k0);
        bf16x8 a1 = *(const bf16x8*)(a1p + k0);
        bf16x8 w0 = *(const bf16x8*)(w0p + k0);
        bf16x8 w1 = *(const bf16x8*)(w1p + k0);
        acc[0][0] = MFMA(a0, w0, acc[0][0]);
        acc[0][1] = MFMA(a0, w1, acc[0][1]);
        acc[1][0] = MFMA(a1, w0, acc[1][0]);
        acc[1][1] = MFMA(a1, w1, acc[1][1]);
    }
    #pragma unroll
    for (int mi = 0; mi < 2; ++mi)
        #pragma unroll
        for (int ni = 0; ni < 2; ++ni)
            #pragma unroll
            for (int r = 0; r < 4; ++r) {
                int row = r0 + mi * 16 + ((lane >> 4) * 4) + r;
                int col = n0 + ni * 16 + (lane & 15);
                out[(size_t)row * OO + col] = acc[mi][ni][r] + bo[col];
            }
}

// ---------------- launch ----------------
extern "C" void kernel_launch(void* const* d_in, const int* in_sizes, int n_in,
                              void* d_out, int out_size, void* d_ws, size_t ws_size,
                              hipStream_t stream) {
    const float* x      = (const float*)d_in[0];
    const float* w_ih_0 = (const float*)d_in[1];
    const float* w_hh_0 = (const float*)d_in[2];
    const float* b_0    = (const float*)d_in[3];
    const float* w_ih_1 = (const float*)d_in[4];
    const float* w_hh_1 = (const float*)d_in[5];
    const float* b_1    = (const float*)d_in[6];
    const float* w_ih_2 = (const float*)d_in[7];
    const float* w_hh_2 = (const float*)d_in[8];
    const float* b_2    = (const float*)d_in[9];
    const float* w_out  = (const float*)d_in[10];
    const float* b_out  = (const float*)d_in[11];
    float* out = (float*)d_out;

    // ---- workspace carve-up ----
    char* ws = (char*)d_ws;
    size_t off = 0;
    __bf16* xb    = (__bf16*)(ws + off); off += (size_t)TT * BB * II * 2;      // 16.8 MB
    __bf16* pw0   = (__bf16*)(ws + off); off += (size_t)2048 * 640 * 2;        // 2.6 MB
    __bf16* pw1   = (__bf16*)(ws + off); off += (size_t)2048 * 1024 * 2;       // 4.2 MB
    __bf16* pw2   = (__bf16*)(ws + off); off += (size_t)2048 * 1024 * 2;
    __bf16* woutb = (__bf16*)(ws + off); off += (size_t)OO * HH * 2;
    __bf16* h0    = (__bf16*)(ws + off); off += (size_t)TT * BB * HH * 2;      // 67 MB
    __bf16* h1    = (__bf16*)(ws + off); off += (size_t)TT * BB * HH * 2;
    __bf16* h2    = (__bf16*)(ws + off); off += (size_t)TT * BB * HH * 2;
    int*    hs    = (int*)(ws + off);    off += (size_t)64 * 4;
    int*    flags = (int*)(ws + off);    off += (size_t)8 * 32 * 32 * 4;       // 32 KB
    (void)ws_size; (void)in_sizes; (void)n_in; (void)out_size;

    // ---- prepack ----
    {
        int n = TT * BB * II;
        cast_f32_bf16<<<(n + 255) / 256, 256, 0, stream>>>(x, xb, n);
        n = OO * HH;
        cast_f32_bf16<<<(n + 255) / 256, 256, 0, stream>>>(w_out, woutb, n);
        int t0 = 2048 * (640 / 8);
        pack_w_kernel<<<(t0 + 255) / 256, 256, 0, stream>>>(w_ih_0, w_hh_0, pw0, II);
        int t1 = 2048 * (1024 / 8);
        pack_w_kernel<<<(t1 + 255) / 256, 256, 0, stream>>>(w_ih_1, w_hh_1, pw1, HH);
        pack_w_kernel<<<(t1 + 255) / 256, 256, 0, stream>>>(w_ih_2, w_hh_2, pw2, HH);
    }
    hipMemsetAsync(hs, 0, (size_t)(64 + 8 * 32 * 32) * 4, stream);

    // ---- persistent pipelined 3-layer LSTM: 256 blocks (1/CU), 8 waves ----
    lstm_persist<<<256, 512, 0, stream>>>(xb, pw0, pw1, pw2, b_0, b_1, b_2,
                                          h0, h1, h2, hs, flags);

    // ---- projection over last WW timesteps ----
    const __bf16* A = h2 + (size_t)(TT - WW) * BB * HH;
    proj_kernel<<<(WW * BB) / 32, 256, 0, stream>>>(A, woutb, b_out, out);
}